// Round 4
// baseline (4258.450 us; speedup 1.0000x reference)
//
#include <hip/hip_runtime.h>
#include <cstdint>

#define NB 4
#define NSEQ 1024
#define DMODEL 768
#define NHEAD 12
#define DHEAD 64
#define NDEPTH 6
#define DFF 3072
#define MROWS (NB * NSEQ)   // 4096

// weight block element offsets (concatenated wq|wk|wv|wo|wi|wof per layer)
#define WQ_OFF 0L
#define WK_OFF 589824L
#define WV_OFF 1179648L
#define WO_OFF 1769472L
#define WI_OFF 2359296L
#define WOF_OFF 4718592L
#define WTOT 7077888L

typedef __attribute__((ext_vector_type(8))) short short8;
typedef __attribute__((ext_vector_type(4))) float floatx4;

static __device__ __forceinline__ float b2f(unsigned short u) {
  union { unsigned int i; float f; } v; v.i = ((unsigned int)u) << 16; return v.f;
}
static __device__ __forceinline__ unsigned short f2b(float f) {
  union { float f; unsigned int i; } v; v.f = f;
  unsigned int x = v.i;
  return (unsigned short)((x + 0x7fffu + ((x >> 16) & 1u)) >> 16);  // RNE
}
// split f32 -> (hi, lo) bf16 pair; hi+lo reconstructs to ~2^-17 rel
static __device__ __forceinline__ void fsplit(float f, unsigned short& h, unsigned short& l) {
  h = f2b(f);
  l = f2b(f - b2f(h));
}

// ---------------- per-layer weight split f32 -> hi/lo bf16
__global__ __launch_bounds__(256) void wsplit_kernel(
    const float* __restrict__ wq, const float* __restrict__ wk,
    const float* __restrict__ wv, const float* __restrict__ wo,
    const float* __restrict__ wi, const float* __restrict__ wof,
    unsigned short* __restrict__ dhi, unsigned short* __restrict__ dlo)
{
  long i = ((long)blockIdx.x * 256 + threadIdx.x) * 4;
  if (i >= WTOT) return;
  const float* src; long off;
  if (i < WK_OFF)       { src = wq;  off = i - WQ_OFF; }
  else if (i < WV_OFF)  { src = wk;  off = i - WK_OFF; }
  else if (i < WO_OFF)  { src = wv;  off = i - WV_OFF; }
  else if (i < WI_OFF)  { src = wo;  off = i - WO_OFF; }
  else if (i < WOF_OFF) { src = wi;  off = i - WI_OFF; }
  else                  { src = wof; off = i - WOF_OFF; }
  float4 f = *(const float4*)(src + off);
  ushort4 h, l;
  fsplit(f.x, h.x, l.x); fsplit(f.y, h.y, l.y);
  fsplit(f.z, h.z, l.z); fsplit(f.w, h.w, l.w);
  *(ushort4*)(dhi + i) = h;
  *(ushort4*)(dlo + i) = l;
}

// ---------------- embedding gather -> split x
__global__ void embed_kernel(const int* __restrict__ tok,
                             const float* __restrict__ emb,
                             unsigned short* __restrict__ xhi,
                             unsigned short* __restrict__ xlo) {
  const int row = blockIdx.x;
  const int t = tok[row];
  const float* src = emb + (long)t * DMODEL;
  for (int d = threadIdx.x; d < DMODEL; d += 256) {
    unsigned short h, l;
    fsplit(src[d], h, l);
    xhi[(long)row * DMODEL + d] = h;
    xlo[(long)row * DMODEL + d] = l;
  }
}

// ---------------- GEMM: C(MxN) = act(alpha * A(MxK) @ W(NxK)^T [+ resid])
// All operands split hi/lo bf16. D = Ah*Wh + Al*Wh + Ah*Wl (lo*lo dropped, ~2^-18).
// 64x64 block tile, 4 waves in 2x2, each wave 32x32 (2x2 of 16x16 MFMA).
template<int RELU, int RESID>
__global__ __launch_bounds__(256) void gemm_bt(
    const unsigned short* __restrict__ Ahi, const unsigned short* __restrict__ Alo,
    const unsigned short* __restrict__ Whi, const unsigned short* __restrict__ Wlo,
    unsigned short* __restrict__ Chi, unsigned short* __restrict__ Clo,
    const unsigned short* __restrict__ Rhi, const unsigned short* __restrict__ Rlo,
    int M, int N, int K, float alpha)
{
  __shared__ unsigned short sAh[64][40];  // +8 pad: 2-way bank alias only (free)
  __shared__ unsigned short sAl[64][40];
  __shared__ unsigned short sBh[64][40];
  __shared__ unsigned short sBl[64][40];

  const int tid = threadIdx.x;
  const int bn = blockIdx.x, bm = blockIdx.y;
  const int srow = tid >> 2;         // 0..63 staging row
  const int skc  = (tid & 3) << 3;   // 0,8,16,24 staging k-offset
  const int wave = tid >> 6;
  const int lane = tid & 63;
  const int wm = wave >> 1, wn = wave & 1;
  const int l16 = lane & 15, q4 = lane >> 4;

  floatx4 acc[2][2];
  #pragma unroll
  for (int i = 0; i < 2; ++i)
    #pragma unroll
    for (int j = 0; j < 2; ++j) {
      floatx4 z = {0.f, 0.f, 0.f, 0.f};
      acc[i][j] = z;
    }

  const long arow = (long)(bm * 64 + srow) * K;
  const long brow = (long)(bn * 64 + srow) * K;

  for (int k0 = 0; k0 < K; k0 += 32) {
    *(short8*)&sAh[srow][skc] = *(const short8*)(Ahi + arow + k0 + skc);
    *(short8*)&sAl[srow][skc] = *(const short8*)(Alo + arow + k0 + skc);
    *(short8*)&sBh[srow][skc] = *(const short8*)(Whi + brow + k0 + skc);
    *(short8*)&sBl[srow][skc] = *(const short8*)(Wlo + brow + k0 + skc);
    __syncthreads();

    short8 a0h = *(const short8*)&sAh[wm * 32 +      l16][q4 * 8];
    short8 a1h = *(const short8*)&sAh[wm * 32 + 16 + l16][q4 * 8];
    short8 a0l = *(const short8*)&sAl[wm * 32 +      l16][q4 * 8];
    short8 a1l = *(const short8*)&sAl[wm * 32 + 16 + l16][q4 * 8];
    short8 b0h = *(const short8*)&sBh[wn * 32 +      l16][q4 * 8];
    short8 b1h = *(const short8*)&sBh[wn * 32 + 16 + l16][q4 * 8];
    short8 b0l = *(const short8*)&sBl[wn * 32 +      l16][q4 * 8];
    short8 b1l = *(const short8*)&sBl[wn * 32 + 16 + l16][q4 * 8];

    acc[0][0] = __builtin_amdgcn_mfma_f32_16x16x32_bf16(a0h, b0h, acc[0][0], 0, 0, 0);
    acc[0][1] = __builtin_amdgcn_mfma_f32_16x16x32_bf16(a0h, b1h, acc[0][1], 0, 0, 0);
    acc[1][0] = __builtin_amdgcn_mfma_f32_16x16x32_bf16(a1h, b0h, acc[1][0], 0, 0, 0);
    acc[1][1] = __builtin_amdgcn_mfma_f32_16x16x32_bf16(a1h, b1h, acc[1][1], 0, 0, 0);
    acc[0][0] = __builtin_amdgcn_mfma_f32_16x16x32_bf16(a0l, b0h, acc[0][0], 0, 0, 0);
    acc[0][1] = __builtin_amdgcn_mfma_f32_16x16x32_bf16(a0l, b1h, acc[0][1], 0, 0, 0);
    acc[1][0] = __builtin_amdgcn_mfma_f32_16x16x32_bf16(a1l, b0h, acc[1][0], 0, 0, 0);
    acc[1][1] = __builtin_amdgcn_mfma_f32_16x16x32_bf16(a1l, b1h, acc[1][1], 0, 0, 0);
    acc[0][0] = __builtin_amdgcn_mfma_f32_16x16x32_bf16(a0h, b0l, acc[0][0], 0, 0, 0);
    acc[0][1] = __builtin_amdgcn_mfma_f32_16x16x32_bf16(a0h, b1l, acc[0][1], 0, 0, 0);
    acc[1][0] = __builtin_amdgcn_mfma_f32_16x16x32_bf16(a1h, b0l, acc[1][0], 0, 0, 0);
    acc[1][1] = __builtin_amdgcn_mfma_f32_16x16x32_bf16(a1h, b1l, acc[1][1], 0, 0, 0);
    __syncthreads();
  }

  // epilogue: C/D layout col=lane&15, row=(lane>>4)*4+reg  [m89/m91 verified]
  #pragma unroll
  for (int mt = 0; mt < 2; ++mt) {
    #pragma unroll
    for (int nt = 0; nt < 2; ++nt) {
      const int r0 = bm * 64 + wm * 32 + mt * 16 + q4 * 4;
      const int c  = bn * 64 + wn * 32 + nt * 16 + l16;
      #pragma unroll
      for (int r = 0; r < 4; ++r) {
        float vv = acc[mt][nt][r] * alpha;
        const long idx = (long)(r0 + r) * N + c;
        if (RESID) vv += b2f(Rhi[idx]) + b2f(Rlo[idx]);
        if (RELU)  vv = fmaxf(vv, 0.f);
        unsigned short h, l;
        fsplit(vv, h, l);
        Chi[idx] = h; Clo[idx] = l;
      }
    }
  }
}

// ---------------- flash attention, f32 math (mask all-ones -> ignored).
// one block = 16 query rows of one (b,h); online softmax over 64-key chunks.
__global__ __launch_bounds__(256) void attn_kernel(
    const unsigned short* __restrict__ qhi, const unsigned short* __restrict__ qlo,
    const unsigned short* __restrict__ khi, const unsigned short* __restrict__ klo,
    const unsigned short* __restrict__ vhi, const unsigned short* __restrict__ vlo,
    unsigned short* __restrict__ ohi, unsigned short* __restrict__ olo)
{
  __shared__ float qs[16][68];
  __shared__ float ks[64][68];
  __shared__ float vs[64][68];
  __shared__ float ps[16][68];
  __shared__ float red[16][16];
  __shared__ float rowm[16], rowl[16], rowa[16];

  const int tid = threadIdx.x;
  const int it = blockIdx.x, h = blockIdx.y, b = blockIdx.z;
  const int ti = tid >> 4, tj = tid & 15;
  const int i0 = it * 16;
  const long base = ((long)b * NSEQ) * DMODEL + h * DHEAD;

  if (tid < 128) {
    int r = tid >> 3, cc = (tid & 7) * 8;
    const long off = base + (long)(i0 + r) * DMODEL + cc;
    short8 hv = *(const short8*)(qhi + off);
    short8 lv = *(const short8*)(qlo + off);
    #pragma unroll
    for (int u = 0; u < 8; ++u)
      qs[r][cc + u] = b2f((unsigned short)hv[u]) + b2f((unsigned short)lv[u]);
  }
  if (tj == 0) { rowm[ti] = -INFINITY; rowl[ti] = 0.f; }
  float oacc[4] = {0.f, 0.f, 0.f, 0.f};
  __syncthreads();

  for (int jc = 0; jc < NSEQ / 64; ++jc) {
    const int j0 = jc * 64;
    #pragma unroll
    for (int half = 0; half < 2; ++half) {
      int r = (tid >> 3) + half * 32;
      int cc = (tid & 7) * 8;
      const long off = base + (long)(j0 + r) * DMODEL + cc;
      short8 kh = *(const short8*)(khi + off);
      short8 kl = *(const short8*)(klo + off);
      short8 vh = *(const short8*)(vhi + off);
      short8 vl = *(const short8*)(vlo + off);
      #pragma unroll
      for (int u = 0; u < 8; ++u) {
        ks[r][cc + u] = b2f((unsigned short)kh[u]) + b2f((unsigned short)kl[u]);
        vs[r][cc + u] = b2f((unsigned short)vh[u]) + b2f((unsigned short)vl[u]);
      }
    }
    __syncthreads();

    float sc[4];
    #pragma unroll
    for (int jj = 0; jj < 4; ++jj) {
      const int j = jj * 16 + tj;
      float s = 0.f;
      #pragma unroll
      for (int d = 0; d < 64; ++d) s = fmaf(qs[ti][d], ks[j][d], s);
      sc[jj] = s;
    }
    float lmax = fmaxf(fmaxf(sc[0], sc[1]), fmaxf(sc[2], sc[3]));
    red[ti][tj] = lmax;
    __syncthreads();
    if (tj == 0) {
      float cm = red[ti][0];
      for (int u = 1; u < 16; ++u) cm = fmaxf(cm, red[ti][u]);
      float mold = rowm[ti];
      float mnew = fmaxf(mold, cm);
      rowa[ti] = __expf(mold - mnew);   // first chunk: exp(-inf)=0
      rowm[ti] = mnew;
    }
    __syncthreads();
    const float mrow = rowm[ti];
    float psum = 0.f;
    #pragma unroll
    for (int jj = 0; jj < 4; ++jj) {
      const int j = jj * 16 + tj;
      float p = __expf(sc[jj] - mrow);
      ps[ti][j] = p;
      psum += p;
    }
    red[ti][tj] = psum;
    __syncthreads();
    if (tj == 0) {
      float s = 0.f;
      for (int u = 0; u < 16; ++u) s += red[ti][u];
      rowl[ti] = rowl[ti] * rowa[ti] + s;
    }
    const float al = rowa[ti];
    #pragma unroll
    for (int c = 0; c < 4; ++c) oacc[c] *= al;
    #pragma unroll 8
    for (int j = 0; j < 64; ++j) {
      const float p = ps[ti][j];
      const float4 vv = *(const float4*)&vs[j][tj * 4];
      oacc[0] = fmaf(p, vv.x, oacc[0]);
      oacc[1] = fmaf(p, vv.y, oacc[1]);
      oacc[2] = fmaf(p, vv.z, oacc[2]);
      oacc[3] = fmaf(p, vv.w, oacc[3]);
    }
    __syncthreads();
  }

  const float inv = 1.f / rowl[ti];
  #pragma unroll
  for (int c = 0; c < 4; ++c) {
    const long idx = base + (long)(i0 + ti) * DMODEL + tj * 4 + c;
    unsigned short hh, ll;
    fsplit(oacc[c] * inv, hh, ll);
    ohi[idx] = hh; olo[idx] = ll;
  }
}

// ---------------- final T5 RMS layernorm, split in -> f32 out
__global__ __launch_bounds__(256) void ln_kernel(const unsigned short* __restrict__ xhi,
                                                 const unsigned short* __restrict__ xlo,
                                                 const float* __restrict__ w,
                                                 float* __restrict__ out)
{
  __shared__ float red[256];
  const int row = blockIdx.x;
  const long rb = (long)row * DMODEL;
  float ss = 0.f;
  for (int d = threadIdx.x; d < DMODEL; d += 256) {
    float v = b2f(xhi[rb + d]) + b2f(xlo[rb + d]);
    ss += v * v;
  }
  red[threadIdx.x] = ss;
  __syncthreads();
  for (int s = 128; s > 0; s >>= 1) {
    if (threadIdx.x < s) red[threadIdx.x] += red[threadIdx.x + s];
    __syncthreads();
  }
  const float rs = rsqrtf(red[0] * (1.f / DMODEL) + 1e-6f);
  for (int d = threadIdx.x; d < DMODEL; d += 256) {
    float v = b2f(xhi[rb + d]) + b2f(xlo[rb + d]);
    out[rb + d] = w[d] * v * rs;
  }
}

extern "C" void kernel_launch(void* const* d_in, const int* in_sizes, int n_in,
                              void* d_out, int out_size, void* d_ws, size_t ws_size,
                              hipStream_t stream)
{
  const int* tokens   = (const int*)d_in[0];
  // d_in[1] = mask (all ones in this problem) — unused
  const float* emb    = (const float*)d_in[2];
  const float* wq     = (const float*)d_in[3];
  const float* wk     = (const float*)d_in[4];
  const float* wv     = (const float*)d_in[5];
  const float* wo     = (const float*)d_in[6];
  const float* wi     = (const float*)d_in[7];
  const float* wof    = (const float*)d_in[8];
  const float* lnw    = (const float*)d_in[9];

  // ws layout (all ushort arrays, sizes in bytes):
  //   x_hi,x_lo              2 x 6.29MB
  //   act block q/k/v/o hi+lo 8 x 6.29MB  (reused as ff1_hi/ff1_lo, 2 x 25.2MB)
  //   w_hi,w_lo              2 x 14.2MB
  const size_t AS = (size_t)MROWS * DMODEL;   // 3,145,728 elems
  char* p = (char*)d_ws;
  unsigned short* xhi = (unsigned short*)p;  p += AS * 2;
  unsigned short* xlo = (unsigned short*)p;  p += AS * 2;
  unsigned short* act = (unsigned short*)p;  p += AS * 2 * 8;
  unsigned short* whi = (unsigned short*)p;  p += (size_t)WTOT * 2;
  unsigned short* wlo = (unsigned short*)p;  p += (size_t)WTOT * 2;

  unsigned short* qhi = act + AS * 0; unsigned short* qlo = act + AS * 1;
  unsigned short* khi = act + AS * 2; unsigned short* klo = act + AS * 3;
  unsigned short* vhi = act + AS * 4; unsigned short* vlo = act + AS * 5;
  unsigned short* ohi = act + AS * 6; unsigned short* olo = act + AS * 7;
  unsigned short* fhi = act + AS * 0; unsigned short* flo = act + AS * 4; // ff1: 4096x3072 each

  embed_kernel<<<MROWS, 256, 0, stream>>>(tokens, emb, xhi, xlo);

  const dim3 g768(DMODEL / 64, MROWS / 64);   // (12,64)
  const dim3 gff(DFF / 64, MROWS / 64);       // (48,64)
  const dim3 gattn(NSEQ / 16, NHEAD, NB);     // (64,12,4)
  const int splitblocks = (int)(WTOT / 1024); // 6912

  for (int l = 0; l < NDEPTH; ++l) {
    wsplit_kernel<<<splitblocks, 256, 0, stream>>>(
        wq  + (size_t)l * DMODEL * DMODEL,
        wk  + (size_t)l * DMODEL * DMODEL,
        wv  + (size_t)l * DMODEL * DMODEL,
        wo  + (size_t)l * DMODEL * DMODEL,
        wi  + (size_t)l * DFF * DMODEL,
        wof + (size_t)l * DMODEL * DFF,
        whi, wlo);

    // q/k/v projections (q pre-scaled by DH^-0.5)
    gemm_bt<0, 0><<<g768, 256, 0, stream>>>(xhi, xlo, whi + WQ_OFF, wlo + WQ_OFF,
                                            qhi, qlo, nullptr, nullptr,
                                            MROWS, DMODEL, DMODEL, 0.125f);
    gemm_bt<0, 0><<<g768, 256, 0, stream>>>(xhi, xlo, whi + WK_OFF, wlo + WK_OFF,
                                            khi, klo, nullptr, nullptr,
                                            MROWS, DMODEL, DMODEL, 1.f);
    gemm_bt<0, 0><<<g768, 256, 0, stream>>>(xhi, xlo, whi + WV_OFF, wlo + WV_OFF,
                                            vhi, vlo, nullptr, nullptr,
                                            MROWS, DMODEL, DMODEL, 1.f);
    // attention
    attn_kernel<<<gattn, 256, 0, stream>>>(qhi, qlo, khi, klo, vhi, vlo, ohi, olo);
    // x = x + attn_out @ wo^T
    gemm_bt<0, 1><<<g768, 256, 0, stream>>>(ohi, olo, whi + WO_OFF, wlo + WO_OFF,
                                            xhi, xlo, xhi, xlo,
                                            MROWS, DMODEL, DMODEL, 1.f);
    // ff1 = relu(x @ wi^T)
    gemm_bt<1, 0><<<gff, 256, 0, stream>>>(xhi, xlo, whi + WI_OFF, wlo + WI_OFF,
                                           fhi, flo, nullptr, nullptr,
                                           MROWS, DFF, DMODEL, 1.f);
    // x = x + ff1 @ wof^T
    gemm_bt<0, 1><<<g768, 256, 0, stream>>>(fhi, flo, whi + WOF_OFF, wlo + WOF_OFF,
                                            xhi, xlo, xhi, xlo,
                                            MROWS, DMODEL, DFF, 1.f);
  }

  ln_kernel<<<MROWS, 256, 0, stream>>>(xhi, xlo, lnw, (float*)d_out);
}